// Round 2
// baseline (589.295 us; speedup 1.0000x reference)
//
#include <hip/hip_runtime.h>

#define N_NODES 50000
#define N_EDGES 800000
#define D 64

__global__ void deg_kernel(const int* __restrict__ dst, float* __restrict__ deg, int E) {
    int e = blockIdx.x * blockDim.x + threadIdx.x;
    if (e < E) atomicAdd(&deg[dst[e]], 1.0f);
}

__global__ void dinv_kernel(const float* __restrict__ deg, float* __restrict__ dinv, int N) {
    int i = blockIdx.x * blockDim.x + threadIdx.x;
    if (i < N) {
        float d = deg[i];
        dinv[i] = d > 0.0f ? rsqrtf(d) : 0.0f;
    }
}

__global__ void w_kernel(const int* __restrict__ src, const int* __restrict__ dst,
                         const float* __restrict__ dinv, float* __restrict__ w, int E) {
    int e = blockIdx.x * blockDim.x + threadIdx.x;
    if (e < E) w[e] = dinv[src[e]] * dinv[dst[e]];
}

// one edge per 64 lanes; block of 256 handles 4 edges.
// y[dst*D + d] += x[src*D + d] * w[e] * scale  (atomic scatter-add)
__global__ void prop_kernel(const int* __restrict__ src, const int* __restrict__ dst,
                            const float* __restrict__ w,
                            const float* __restrict__ x, float* __restrict__ y,
                            int E, float scale) {
    int t = blockIdx.x * blockDim.x + threadIdx.x;
    int e = t >> 6;
    int d = t & 63;
    if (e < E) {
        int s  = src[e];
        int dd = dst[e];
        float val = x[s * D + d] * (w[e] * scale);
        atomicAdd(&y[dd * D + d], val);
    }
}

__global__ void combine_kernel(const float* __restrict__ x0, const float* __restrict__ x1,
                               const float* __restrict__ x2, float* __restrict__ out, int n) {
    int i = blockIdx.x * blockDim.x + threadIdx.x;
    if (i < n) out[i] = (x0[i] + x1[i] + x2[i]) * 0.25f;
}

extern "C" void kernel_launch(void* const* d_in, const int* in_sizes, int n_in,
                              void* d_out, int out_size, void* d_ws, size_t ws_size,
                              hipStream_t stream) {
    const int*   ei  = (const int*)d_in[0];     // (2, E) int32, row-major
    const float* emb = (const float*)d_in[1];   // (N, D) fp32
    const int* src = ei;
    const int* dst = ei + N_EDGES;
    float* out = (float*)d_out;

    // workspace layout (floats): deg[N] | dinv[N] | w[E] | x1[N*D] | x2[N*D]
    float* deg  = (float*)d_ws;
    float* dinv = deg + N_NODES;
    float* w    = dinv + N_NODES;
    float* x1   = w + N_EDGES;
    float* x2   = x1 + (size_t)N_NODES * D;

    hipMemsetAsync(deg, 0, N_NODES * sizeof(float), stream);
    hipMemsetAsync(x1, 0, (size_t)2 * N_NODES * D * sizeof(float), stream);

    deg_kernel<<<(N_EDGES + 255) / 256, 256, 0, stream>>>(dst, deg, N_EDGES);
    dinv_kernel<<<(N_NODES + 255) / 256, 256, 0, stream>>>(deg, dinv, N_NODES);
    w_kernel<<<(N_EDGES + 255) / 256, 256, 0, stream>>>(src, dst, dinv, w, N_EDGES);

    const int prop_blocks = (N_EDGES * 64) / 256;   // 200000
    // x1 = A_hat @ x0
    prop_kernel<<<prop_blocks, 256, 0, stream>>>(src, dst, w, emb, x1, N_EDGES, 1.0f);
    // x2 = A_hat @ x1
    prop_kernel<<<prop_blocks, 256, 0, stream>>>(src, dst, w, x1, x2, N_EDGES, 1.0f);
    // out = (x0 + x1 + x2) / 4
    combine_kernel<<<((size_t)N_NODES * D + 255) / 256, 256, 0, stream>>>(emb, x1, x2, out, N_NODES * D);
    // out += (A_hat @ x2) / 4
    prop_kernel<<<prop_blocks, 256, 0, stream>>>(src, dst, w, x2, out, N_EDGES, 0.25f);
}

// Round 3
// 359.307 us; speedup vs baseline: 1.6401x; 1.6401x over previous
//
#include <hip/hip_runtime.h>

#define N_NODES 50000
#define N_EDGES 800000
#define D 64
#define SCAN_THREADS 1024

// ---- CSR build -------------------------------------------------------------

__global__ void hist_kernel(const int* __restrict__ dst, int* __restrict__ cnt, int E) {
    int e = blockIdx.x * blockDim.x + threadIdx.x;
    if (e < E) atomicAdd(&cnt[dst[e]], 1);
}

// single-block exclusive scan over cnt[N] -> rowptr[N+1]; also seed next[] = rowptr[]
__global__ void scan_kernel(const int* __restrict__ cnt, int* __restrict__ rowptr,
                            int* __restrict__ next) {
    __shared__ int part[SCAN_THREADS];
    int t = threadIdx.x;
    const int per = (N_NODES + SCAN_THREADS - 1) / SCAN_THREADS;  // 49
    int beg = t * per;
    int end = beg + per; if (end > N_NODES) end = N_NODES;
    int sum = 0;
    for (int i = beg; i < end; ++i) sum += cnt[i];
    part[t] = sum;
    __syncthreads();
    // Hillis-Steele inclusive scan
    for (int off = 1; off < SCAN_THREADS; off <<= 1) {
        int v = (t >= off) ? part[t - off] : 0;
        __syncthreads();
        part[t] += v;
        __syncthreads();
    }
    int run = (t == 0) ? 0 : part[t - 1];   // exclusive prefix of this chunk
    for (int i = beg; i < end; ++i) {
        rowptr[i] = run;
        next[i]   = run;
        run += cnt[i];
    }
    if (t == SCAN_THREADS - 1) rowptr[N_NODES] = run;   // == E
}

__global__ void dinv_kernel(const int* __restrict__ cnt, float* __restrict__ dinv, int N) {
    int i = blockIdx.x * blockDim.x + threadIdx.x;
    if (i < N) {
        int d = cnt[i];
        dinv[i] = d > 0 ? rsqrtf((float)d) : 0.0f;
    }
}

__global__ void scatter_kernel(const int* __restrict__ src, const int* __restrict__ dst,
                               const float* __restrict__ dinv,
                               int* __restrict__ next,
                               int* __restrict__ csr_src, float* __restrict__ csr_w, int E) {
    int e = blockIdx.x * blockDim.x + threadIdx.x;
    if (e < E) {
        int s = src[e];
        int d = dst[e];
        int pos = atomicAdd(&next[d], 1);
        csr_src[pos] = s;
        csr_w[pos]   = dinv[s] * dinv[d];
    }
}

// ---- pull-based propagation (one wave per dst node, lane = dim) ------------
// MODE 1: x_out[n] = acc;           out[n] = 0.25*(emb[n] + acc)
// MODE 2: x_out[n] = acc;           out[n] += 0.25*acc
// MODE 3:                           out[n] += 0.25*acc
template <int MODE>
__global__ __launch_bounds__(256) void pull_kernel(
        const int* __restrict__ rowptr,
        const int* __restrict__ csr_src, const float* __restrict__ csr_w,
        const float* __restrict__ x, const float* __restrict__ emb,
        float* __restrict__ x_out, float* __restrict__ out) {
    int node = blockIdx.x * 4 + (threadIdx.x >> 6);
    int lane = threadIdx.x & 63;
    if (node >= N_NODES) return;
    int e   = rowptr[node];
    int end = rowptr[node + 1];
    float acc = 0.0f;
    // unroll by 2 for memory-level parallelism
    for (; e + 1 < end; e += 2) {
        int   s0 = csr_src[e],     s1 = csr_src[e + 1];
        float w0 = csr_w[e],       w1 = csr_w[e + 1];
        float v0 = x[s0 * D + lane];
        float v1 = x[s1 * D + lane];
        acc = fmaf(v0, w0, acc);
        acc = fmaf(v1, w1, acc);
    }
    if (e < end) {
        acc = fmaf(x[csr_src[e] * D + lane], csr_w[e], acc);
    }
    int idx = node * D + lane;
    if (MODE == 1) {
        x_out[idx] = acc;
        out[idx] = 0.25f * (emb[idx] + acc);
    } else if (MODE == 2) {
        x_out[idx] = acc;
        out[idx] += 0.25f * acc;
    } else {
        out[idx] += 0.25f * acc;
    }
}

extern "C" void kernel_launch(void* const* d_in, const int* in_sizes, int n_in,
                              void* d_out, int out_size, void* d_ws, size_t ws_size,
                              hipStream_t stream) {
    const int*   ei  = (const int*)d_in[0];     // (2, E) int32, row-major
    const float* emb = (const float*)d_in[1];   // (N, D) fp32
    const int* src = ei;
    const int* dst = ei + N_EDGES;
    float* out = (float*)d_out;

    // workspace layout
    int*   cnt     = (int*)d_ws;                       // N
    int*   rowptr  = cnt + N_NODES;                    // N+1
    int*   next    = rowptr + (N_NODES + 1);           // N
    int*   csr_src = next + N_NODES;                   // E
    float* csr_w   = (float*)(csr_src + N_EDGES);      // E
    float* dinv    = csr_w + N_EDGES;                  // N
    float* x1      = dinv + N_NODES;                   // N*D
    float* x2      = x1 + (size_t)N_NODES * D;         // N*D

    hipMemsetAsync(cnt, 0, N_NODES * sizeof(int), stream);

    hist_kernel<<<(N_EDGES + 255) / 256, 256, 0, stream>>>(dst, cnt, N_EDGES);
    scan_kernel<<<1, SCAN_THREADS, 0, stream>>>(cnt, rowptr, next);
    dinv_kernel<<<(N_NODES + 255) / 256, 256, 0, stream>>>(cnt, dinv, N_NODES);
    scatter_kernel<<<(N_EDGES + 255) / 256, 256, 0, stream>>>(src, dst, dinv, next,
                                                              csr_src, csr_w, N_EDGES);

    const int pull_blocks = (N_NODES + 3) / 4;   // 4 nodes (waves) per 256-thread block
    // x1 = A x0 ; out = 0.25*(x0 + x1)
    pull_kernel<1><<<pull_blocks, 256, 0, stream>>>(rowptr, csr_src, csr_w, emb, emb, x1, out);
    // x2 = A x1 ; out += 0.25*x2
    pull_kernel<2><<<pull_blocks, 256, 0, stream>>>(rowptr, csr_src, csr_w, x1, emb, x2, out);
    // out += 0.25 * (A x2)
    pull_kernel<3><<<pull_blocks, 256, 0, stream>>>(rowptr, csr_src, csr_w, x2, emb, nullptr, out);
}

// Round 4
// 258.703 us; speedup vs baseline: 2.2779x; 1.3889x over previous
//
#include <hip/hip_runtime.h>

#define N_NODES 50000
#define N_EDGES 800000
#define D 64
#define SCAN_BLK 256
#define SCAN_NBLK ((N_NODES + SCAN_BLK - 1) / SCAN_BLK)   // 196

// ---- CSR build -------------------------------------------------------------

__global__ void hist_kernel(const int* __restrict__ dst, int* __restrict__ cnt, int E) {
    int e = blockIdx.x * blockDim.x + threadIdx.x;
    if (e < E) atomicAdd(&cnt[dst[e]], 1);
}

// stage 1: per-block sum of cnt -> blocksum[SCAN_NBLK]
__global__ __launch_bounds__(SCAN_BLK) void scan_partial(const int* __restrict__ cnt,
                                                         int* __restrict__ blocksum) {
    __shared__ int lds[4];
    int i = blockIdx.x * SCAN_BLK + threadIdx.x;
    int v = (i < N_NODES) ? cnt[i] : 0;
    // wave reduce (64 lanes)
    for (int off = 32; off > 0; off >>= 1) v += __shfl_down(v, off, 64);
    int wid = threadIdx.x >> 6;
    if ((threadIdx.x & 63) == 0) lds[wid] = v;
    __syncthreads();
    if (threadIdx.x == 0)
        blocksum[blockIdx.x] = lds[0] + lds[1] + lds[2] + lds[3];
}

// stage 2: single block exclusive-scans blocksum -> blockoff
__global__ __launch_bounds__(SCAN_BLK) void scan_bsum(int* __restrict__ blocksum,
                                                      int* __restrict__ blockoff) {
    __shared__ int lds[SCAN_BLK];
    int t = threadIdx.x;
    int v = (t < SCAN_NBLK) ? blocksum[t] : 0;
    lds[t] = v;
    __syncthreads();
    for (int off = 1; off < SCAN_BLK; off <<= 1) {
        int u = (t >= off) ? lds[t - off] : 0;
        __syncthreads();
        lds[t] += u;
        __syncthreads();
    }
    if (t < SCAN_NBLK) blockoff[t] = lds[t] - v;   // exclusive
}

// stage 3: per-block exclusive scan + offset -> rowptr, next; fused dinv
__global__ __launch_bounds__(SCAN_BLK) void scan_final(const int* __restrict__ cnt,
                                                       const int* __restrict__ blockoff,
                                                       int* __restrict__ rowptr,
                                                       int* __restrict__ next,
                                                       float* __restrict__ dinv) {
    __shared__ int lds[SCAN_BLK];
    int t = threadIdx.x;
    int i = blockIdx.x * SCAN_BLK + t;
    int v = (i < N_NODES) ? cnt[i] : 0;
    lds[t] = v;
    __syncthreads();
    for (int off = 1; off < SCAN_BLK; off <<= 1) {
        int u = (t >= off) ? lds[t - off] : 0;
        __syncthreads();
        lds[t] += u;
        __syncthreads();
    }
    if (i < N_NODES) {
        int pos = blockoff[blockIdx.x] + lds[t] - v;   // exclusive prefix
        rowptr[i] = pos;
        next[i]   = pos;
        dinv[i]   = v > 0 ? rsqrtf((float)v) : 0.0f;
        if (i == N_NODES - 1) rowptr[N_NODES] = pos + v;   // == E
    }
}

__global__ void scatter_kernel(const int* __restrict__ src, const int* __restrict__ dst,
                               const float* __restrict__ dinv,
                               int* __restrict__ next,
                               int* __restrict__ csr_src, float* __restrict__ csr_w, int E) {
    int e = blockIdx.x * blockDim.x + threadIdx.x;
    if (e < E) {
        int s = src[e];
        int d = dst[e];
        int pos = atomicAdd(&next[d], 1);
        csr_src[pos] = s;
        csr_w[pos]   = dinv[s] * dinv[d];
    }
}

// ---- pull-based propagation (one wave per dst node, lane = dim) ------------
// MODE 1: x_out[n] = acc;           out[n] = 0.25*(emb[n] + acc)
// MODE 2: x_out[n] = acc;           out[n] += 0.25*acc
// MODE 3:                           out[n] += 0.25*acc
template <int MODE>
__global__ __launch_bounds__(256) void pull_kernel(
        const int* __restrict__ rowptr,
        const int* __restrict__ csr_src, const float* __restrict__ csr_w,
        const float* __restrict__ x, const float* __restrict__ emb,
        float* __restrict__ x_out, float* __restrict__ out) {
    int node = blockIdx.x * 4 + (threadIdx.x >> 6);
    int lane = threadIdx.x & 63;
    if (node >= N_NODES) return;
    int e   = rowptr[node];
    int end = rowptr[node + 1];
    float acc = 0.0f;
    for (; e + 1 < end; e += 2) {
        int   s0 = csr_src[e],     s1 = csr_src[e + 1];
        float w0 = csr_w[e],       w1 = csr_w[e + 1];
        float v0 = x[s0 * D + lane];
        float v1 = x[s1 * D + lane];
        acc = fmaf(v0, w0, acc);
        acc = fmaf(v1, w1, acc);
    }
    if (e < end) {
        acc = fmaf(x[csr_src[e] * D + lane], csr_w[e], acc);
    }
    int idx = node * D + lane;
    if (MODE == 1) {
        x_out[idx] = acc;
        out[idx] = 0.25f * (emb[idx] + acc);
    } else if (MODE == 2) {
        x_out[idx] = acc;
        out[idx] += 0.25f * acc;
    } else {
        out[idx] += 0.25f * acc;
    }
}

extern "C" void kernel_launch(void* const* d_in, const int* in_sizes, int n_in,
                              void* d_out, int out_size, void* d_ws, size_t ws_size,
                              hipStream_t stream) {
    const int*   ei  = (const int*)d_in[0];     // (2, E) int32, row-major
    const float* emb = (const float*)d_in[1];   // (N, D) fp32
    const int* src = ei;
    const int* dst = ei + N_EDGES;
    float* out = (float*)d_out;

    // workspace layout
    int*   cnt      = (int*)d_ws;                      // N
    int*   rowptr   = cnt + N_NODES;                   // N+1
    int*   next     = rowptr + (N_NODES + 1);          // N
    int*   blocksum = next + N_NODES;                  // SCAN_NBLK
    int*   blockoff = blocksum + SCAN_NBLK;            // SCAN_NBLK
    int*   csr_src  = blockoff + SCAN_NBLK;            // E
    float* csr_w    = (float*)(csr_src + N_EDGES);     // E
    float* dinv     = csr_w + N_EDGES;                 // N
    float* x1       = dinv + N_NODES;                  // N*D
    float* x2       = x1 + (size_t)N_NODES * D;        // N*D

    hipMemsetAsync(cnt, 0, N_NODES * sizeof(int), stream);

    hist_kernel<<<(N_EDGES + 255) / 256, 256, 0, stream>>>(dst, cnt, N_EDGES);
    scan_partial<<<SCAN_NBLK, SCAN_BLK, 0, stream>>>(cnt, blocksum);
    scan_bsum<<<1, SCAN_BLK, 0, stream>>>(blocksum, blockoff);
    scan_final<<<SCAN_NBLK, SCAN_BLK, 0, stream>>>(cnt, blockoff, rowptr, next, dinv);
    scatter_kernel<<<(N_EDGES + 255) / 256, 256, 0, stream>>>(src, dst, dinv, next,
                                                              csr_src, csr_w, N_EDGES);

    const int pull_blocks = (N_NODES + 3) / 4;   // 4 nodes (waves) per 256-thread block
    // x1 = A x0 ; out = 0.25*(x0 + x1)
    pull_kernel<1><<<pull_blocks, 256, 0, stream>>>(rowptr, csr_src, csr_w, emb, emb, x1, out);
    // x2 = A x1 ; out += 0.25*x2
    pull_kernel<2><<<pull_blocks, 256, 0, stream>>>(rowptr, csr_src, csr_w, x1, emb, x2, out);
    // out += 0.25 * (A x2)
    pull_kernel<3><<<pull_blocks, 256, 0, stream>>>(rowptr, csr_src, csr_w, x2, emb, nullptr, out);
}

// Round 5
// 208.384 us; speedup vs baseline: 2.8279x; 1.2415x over previous
//
#include <hip/hip_runtime.h>
#include <hip/hip_fp16.h>

#define N_NODES 50000
#define N_EDGES 800000
#define D 64
#define SCAN_BLK 256
#define SCAN_NBLK ((N_NODES + SCAN_BLK - 1) / SCAN_BLK)   // 196

// ---- CSR build -------------------------------------------------------------

__global__ void hist_kernel(const int* __restrict__ dst, int* __restrict__ cnt, int E) {
    int e = blockIdx.x * blockDim.x + threadIdx.x;
    if (e < E) atomicAdd(&cnt[dst[e]], 1);
}

__global__ __launch_bounds__(SCAN_BLK) void scan_partial(const int* __restrict__ cnt,
                                                         int* __restrict__ blocksum) {
    __shared__ int lds[4];
    int i = blockIdx.x * SCAN_BLK + threadIdx.x;
    int v = (i < N_NODES) ? cnt[i] : 0;
    for (int off = 32; off > 0; off >>= 1) v += __shfl_down(v, off, 64);
    int wid = threadIdx.x >> 6;
    if ((threadIdx.x & 63) == 0) lds[wid] = v;
    __syncthreads();
    if (threadIdx.x == 0)
        blocksum[blockIdx.x] = lds[0] + lds[1] + lds[2] + lds[3];
}

__global__ __launch_bounds__(SCAN_BLK) void scan_bsum(int* __restrict__ blocksum,
                                                      int* __restrict__ blockoff) {
    __shared__ int lds[SCAN_BLK];
    int t = threadIdx.x;
    int v = (t < SCAN_NBLK) ? blocksum[t] : 0;
    lds[t] = v;
    __syncthreads();
    for (int off = 1; off < SCAN_BLK; off <<= 1) {
        int u = (t >= off) ? lds[t - off] : 0;
        __syncthreads();
        lds[t] += u;
        __syncthreads();
    }
    if (t < SCAN_NBLK) blockoff[t] = lds[t] - v;   // exclusive
}

// per-block exclusive scan + offset -> rowptr, next; fused dinv
__global__ __launch_bounds__(SCAN_BLK) void scan_final(const int* __restrict__ cnt,
                                                       const int* __restrict__ blockoff,
                                                       int* __restrict__ rowptr,
                                                       int* __restrict__ next,
                                                       float* __restrict__ dinv) {
    __shared__ int lds[SCAN_BLK];
    int t = threadIdx.x;
    int i = blockIdx.x * SCAN_BLK + t;
    int v = (i < N_NODES) ? cnt[i] : 0;
    lds[t] = v;
    __syncthreads();
    for (int off = 1; off < SCAN_BLK; off <<= 1) {
        int u = (t >= off) ? lds[t - off] : 0;
        __syncthreads();
        lds[t] += u;
        __syncthreads();
    }
    if (i < N_NODES) {
        int pos = blockoff[blockIdx.x] + lds[t] - v;
        rowptr[i] = pos;
        next[i]   = pos;
        dinv[i]   = v > 0 ? rsqrtf((float)v) : 0.0f;
        if (i == N_NODES - 1) rowptr[N_NODES] = pos + v;   // == E
    }
}

// indices fit in 16 bits (N_NODES < 65536): half the scatter write traffic
__global__ void scatter_kernel(const int* __restrict__ src, const int* __restrict__ dst,
                               int* __restrict__ next, unsigned short* __restrict__ csr_src,
                               int E) {
    int e = blockIdx.x * blockDim.x + threadIdx.x;
    if (e < E) {
        int pos = atomicAdd(&next[dst[e]], 1);
        csr_src[pos] = (unsigned short)src[e];
    }
}

// y0 = dinv[node] * emb, stored fp16. Each thread: 4 elems (float4 in, 2x half2 out)
__global__ void scale_kernel(const float* __restrict__ emb, const float* __restrict__ dinv,
                             __half* __restrict__ y, int total4) {
    int i = blockIdx.x * blockDim.x + threadIdx.x;
    if (i < total4) {
        float4 v = ((const float4*)emb)[i];
        float s = dinv[(i * 4) / D];
        __half2 h0 = __floats2half2_rn(v.x * s, v.y * s);
        __half2 h1 = __floats2half2_rn(v.z * s, v.w * s);
        ((__half2*)y)[2 * i]     = h0;
        ((__half2*)y)[2 * i + 1] = h1;
    }
}

// ---- pull propagation in scaled space (one wave per dst node, lane = dim) --
// acc = sum_{e->node} y[src_e];  x_{k+1} = dinv*acc;  y_{k+1} = dinv*x_{k+1}
// MODE 1: out = 0.25*(emb + x);  y_out = dinv*x
// MODE 2: out += 0.25*x;         y_out = dinv*x
// MODE 3: out += 0.25*x
template <int MODE>
__global__ __launch_bounds__(256) void pull_kernel(
        const int* __restrict__ rowptr, const unsigned short* __restrict__ csr_src,
        const float* __restrict__ dinv, const __half* __restrict__ y,
        const float* __restrict__ emb, __half* __restrict__ y_out,
        float* __restrict__ out) {
    int node = blockIdx.x * 4 + (threadIdx.x >> 6);
    int lane = threadIdx.x & 63;
    if (node >= N_NODES) return;
    int e   = rowptr[node];
    int end = rowptr[node + 1];
    float acc = 0.0f;
    for (; e + 3 < end; e += 4) {
        int s0 = csr_src[e],     s1 = csr_src[e + 1];
        int s2 = csr_src[e + 2], s3 = csr_src[e + 3];
        float v0 = __half2float(y[s0 * D + lane]);
        float v1 = __half2float(y[s1 * D + lane]);
        float v2 = __half2float(y[s2 * D + lane]);
        float v3 = __half2float(y[s3 * D + lane]);
        acc += (v0 + v1) + (v2 + v3);
    }
    for (; e < end; ++e) acc += __half2float(y[csr_src[e] * D + lane]);

    float dn = dinv[node];
    float x  = dn * acc;
    int idx  = node * D + lane;
    if (MODE == 1) {
        out[idx]   = 0.25f * (emb[idx] + x);
        y_out[idx] = __float2half(dn * x);
    } else if (MODE == 2) {
        out[idx]  += 0.25f * x;
        y_out[idx] = __float2half(dn * x);
    } else {
        out[idx]  += 0.25f * x;
    }
}

extern "C" void kernel_launch(void* const* d_in, const int* in_sizes, int n_in,
                              void* d_out, int out_size, void* d_ws, size_t ws_size,
                              hipStream_t stream) {
    const int*   ei  = (const int*)d_in[0];     // (2, E) int32, row-major
    const float* emb = (const float*)d_in[1];   // (N, D) fp32
    const int* src = ei;
    const int* dst = ei + N_EDGES;
    float* out = (float*)d_out;

    // workspace layout
    int* cnt      = (int*)d_ws;                          // N
    int* rowptr   = cnt + N_NODES;                       // N+1
    int* next     = rowptr + (N_NODES + 1);              // N
    int* blocksum = next + N_NODES;                      // 196
    int* blockoff = blocksum + SCAN_NBLK;                // 196
    unsigned short* csr_src = (unsigned short*)(blockoff + SCAN_NBLK);   // E (2B)
    float*  dinv = (float*)(csr_src + N_EDGES);          // N
    __half* y0   = (__half*)(dinv + N_NODES);            // N*D (2B)
    __half* y1   = y0 + (size_t)N_NODES * D;             // N*D
    __half* y2   = y1 + (size_t)N_NODES * D;             // N*D

    hipMemsetAsync(cnt, 0, N_NODES * sizeof(int), stream);

    hist_kernel<<<(N_EDGES + 255) / 256, 256, 0, stream>>>(dst, cnt, N_EDGES);
    scan_partial<<<SCAN_NBLK, SCAN_BLK, 0, stream>>>(cnt, blocksum);
    scan_bsum<<<1, SCAN_BLK, 0, stream>>>(blocksum, blockoff);
    scan_final<<<SCAN_NBLK, SCAN_BLK, 0, stream>>>(cnt, blockoff, rowptr, next, dinv);
    scatter_kernel<<<(N_EDGES + 255) / 256, 256, 0, stream>>>(src, dst, next, csr_src, N_EDGES);
    scale_kernel<<<((N_NODES * D / 4) + 255) / 256, 256, 0, stream>>>(emb, dinv, y0, N_NODES * D / 4);

    const int pull_blocks = (N_NODES + 3) / 4;
    // x1: out = 0.25*(x0+x1), y1
    pull_kernel<1><<<pull_blocks, 256, 0, stream>>>(rowptr, csr_src, dinv, y0, emb, y1, out);
    // x2: out += 0.25*x2, y2
    pull_kernel<2><<<pull_blocks, 256, 0, stream>>>(rowptr, csr_src, dinv, y1, emb, y2, out);
    // x3: out += 0.25*x3
    pull_kernel<3><<<pull_blocks, 256, 0, stream>>>(rowptr, csr_src, dinv, y2, emb, nullptr, out);
}

// Round 6
// 162.433 us; speedup vs baseline: 3.6279x; 1.2829x over previous
//
#include <hip/hip_runtime.h>
#include <hip/hip_fp16.h>

#define N_NODES 50000
#define N_EDGES 800000
#define D 64
#define NBUCK 196                 // ceil(N_NODES / 256)
#define BUCK_SHIFT 8
#define PA_CHUNK 2048
#define PA_BLOCKS ((N_EDGES + PA_CHUNK - 1) / PA_CHUNK)   // 391
#define PB_CAP 8192               // Poisson(4082) never reaches this; fallback kept anyway

// ---- tiny init -------------------------------------------------------------
__global__ void zero_bhist(int* __restrict__ bhist) {
    int t = threadIdx.x;
    if (t < NBUCK) bhist[t] = 0;
}

// ---- coarse 196-bucket histogram of dst (LDS-privatized) -------------------
__global__ __launch_bounds__(256) void bucket_hist(const int* __restrict__ dst,
                                                   int* __restrict__ bhist) {
    __shared__ int h[NBUCK];
    for (int i = threadIdx.x; i < NBUCK; i += 256) h[i] = 0;
    __syncthreads();
    int stride = gridDim.x * 256;
    for (int e = blockIdx.x * 256 + threadIdx.x; e < N_EDGES; e += stride)
        atomicAdd(&h[dst[e] >> BUCK_SHIFT], 1);
    __syncthreads();
    for (int i = threadIdx.x; i < NBUCK; i += 256)
        if (h[i]) atomicAdd(&bhist[i], h[i]);
}

// ---- 1-block scan of 196 bucket counts -> bucketoff / bnext ---------------
__global__ __launch_bounds__(256) void bucket_scan(const int* __restrict__ bhist,
                                                   int* __restrict__ bucketoff,
                                                   int* __restrict__ bnext,
                                                   int* __restrict__ rowptr) {
    __shared__ int lds[256];
    int t = threadIdx.x;
    int v = (t < NBUCK) ? bhist[t] : 0;
    lds[t] = v;
    __syncthreads();
    for (int off = 1; off < 256; off <<= 1) {
        int u = (t >= off) ? lds[t - off] : 0;
        __syncthreads();
        lds[t] += u;
        __syncthreads();
    }
    if (t < NBUCK) { bucketoff[t] = lds[t] - v; bnext[t] = lds[t] - v; }
    if (t == 0)    { bucketoff[NBUCK] = N_EDGES; rowptr[N_NODES] = N_EDGES; }
}

// ---- pass A: bin edges by dst>>8 into tmp regions (block-privatized) -------
__global__ __launch_bounds__(256) void pass_a(const int* __restrict__ src,
                                              const int* __restrict__ dst,
                                              int* __restrict__ bnext,
                                              unsigned int* __restrict__ tmp) {
    __shared__ int cnt[NBUCK], loc[NBUCK], cur[NBUCK], gbase[NBUCK];
    __shared__ int s[256];
    __shared__ unsigned int stage[PA_CHUNK];
    __shared__ unsigned char sb[PA_CHUNK];
    int t = threadIdx.x;
    int base = blockIdx.x * PA_CHUNK;
    int len = N_EDGES - base; if (len > PA_CHUNK) len = PA_CHUNK;

    for (int i = t; i < NBUCK; i += 256) cnt[i] = 0;
    __syncthreads();
    for (int j = t; j < len; j += 256)
        atomicAdd(&cnt[dst[base + j] >> BUCK_SHIFT], 1);
    __syncthreads();
    // exclusive scan of cnt over 196 entries
    int v = (t < NBUCK) ? cnt[t] : 0;
    s[t] = v;
    __syncthreads();
    for (int off = 1; off < 256; off <<= 1) {
        int u = (t >= off) ? s[t - off] : 0;
        __syncthreads();
        s[t] += u;
        __syncthreads();
    }
    if (t < NBUCK) {
        loc[t] = s[t] - v;
        cur[t] = s[t] - v;
        gbase[t] = v ? atomicAdd(&bnext[t], v) : 0;
    }
    __syncthreads();
    // group chunk by bucket in LDS
    for (int j = t; j < len; j += 256) {
        int d = dst[base + j], s0 = src[base + j];
        int b = d >> BUCK_SHIFT;
        int r = atomicAdd(&cur[b], 1);
        stage[r] = ((unsigned)d << 16) | (unsigned)s0;
        sb[r] = (unsigned char)b;
    }
    __syncthreads();
    // stream grouped runs to global (mostly consecutive addresses)
    for (int j = t; j < len; j += 256) {
        int b = sb[j];
        tmp[gbase[b] + (j - loc[b])] = stage[j];
    }
}

// ---- pass B: per-bucket in-LDS counting sort -> csr_src, rowptr, dinv, rsq -
__global__ __launch_bounds__(256) void pass_b(const unsigned int* __restrict__ tmp,
                                              const int* __restrict__ bucketoff,
                                              int* __restrict__ rowptr,
                                              float* __restrict__ dinv,
                                              float* __restrict__ rsq,
                                              unsigned short* __restrict__ csr_src) {
    __shared__ int hist[256], ptr[256], cur[256];
    __shared__ unsigned int in[PB_CAP];
    __shared__ unsigned short outs[PB_CAP];
    int b = blockIdx.x, t = threadIdx.x;
    int base = bucketoff[b], end = bucketoff[b + 1];
    int k = end - base;
    int node0 = b << BUCK_SHIFT;
    int nloc = N_NODES - node0; if (nloc > 256) nloc = 256;

    hist[t] = 0;
    __syncthreads();
    bool fits = (k <= PB_CAP);
    for (int j = t; j < k; j += 256) {
        unsigned int w = tmp[base + j];
        if (fits) in[j] = w;
        atomicAdd(&hist[(w >> 16) & 255], 1);
    }
    __syncthreads();
    int v = hist[t];
    ptr[t] = v;
    __syncthreads();
    for (int off = 1; off < 256; off <<= 1) {
        int u = (t >= off) ? ptr[t - off] : 0;
        __syncthreads();
        ptr[t] += u;
        __syncthreads();
    }
    int excl = ptr[t] - v;
    cur[t] = excl;
    if (t < nloc) {
        rowptr[node0 + t] = base + excl;
        dinv[node0 + t] = v > 0 ? rsqrtf((float)v) : 0.0f;
        rsq[node0 + t]  = sqrtf((float)v);
    }
    __syncthreads();
    if (fits) {
        for (int j = t; j < k; j += 256) {
            unsigned int w = in[j];
            int r = atomicAdd(&cur[(w >> 16) & 255], 1);
            outs[r] = (unsigned short)(w & 0xFFFF);
        }
        __syncthreads();
        for (int j = t; j < k; j += 256) csr_src[base + j] = outs[j];
    } else {          // overflow safety net (never expected)
        for (int j = t; j < k; j += 256) {
            unsigned int w = tmp[base + j];
            int r = atomicAdd(&cur[(w >> 16) & 255], 1);
            csr_src[base + r] = (unsigned short)(w & 0xFFFF);
        }
    }
}

// ---- y0 = dinv[node] * emb (fp16) ------------------------------------------
__global__ void scale_kernel(const float* __restrict__ emb, const float* __restrict__ dinv,
                             __half* __restrict__ y, int total4) {
    int i = blockIdx.x * blockDim.x + threadIdx.x;
    if (i < total4) {
        float4 v = ((const float4*)emb)[i];
        float s = dinv[(i * 4) / D];
        ((__half2*)y)[2 * i]     = __floats2half2_rn(v.x * s, v.y * s);
        ((__half2*)y)[2 * i + 1] = __floats2half2_rn(v.z * s, v.w * s);
    }
}

// ---- pull (one wave per dst node, lane = dim) ------------------------------
// FINAL=0: y_out = dinv^2 * acc       (produces y_{k+1})
// FINAL=1: x3 = dinv*acc; out = 0.25*(emb + rsq*(y1+y2) + x3)
template <int FINAL>
__global__ __launch_bounds__(256) void pull_kernel(
        const int* __restrict__ rowptr, const unsigned short* __restrict__ csr_src,
        const float* __restrict__ dinv, const __half* __restrict__ y,
        __half* __restrict__ y_out,
        const float* __restrict__ rsq, const __half* __restrict__ y1,
        const __half* __restrict__ y2, const float* __restrict__ emb,
        float* __restrict__ out) {
    int node = blockIdx.x * 4 + (threadIdx.x >> 6);
    int lane = threadIdx.x & 63;
    if (node >= N_NODES) return;
    int e   = rowptr[node];
    int end = rowptr[node + 1];
    float acc = 0.0f;
    for (; e + 3 < end; e += 4) {
        int s0 = csr_src[e],     s1 = csr_src[e + 1];
        int s2 = csr_src[e + 2], s3 = csr_src[e + 3];
        float v0 = __half2float(y[s0 * D + lane]);
        float v1 = __half2float(y[s1 * D + lane]);
        float v2 = __half2float(y[s2 * D + lane]);
        float v3 = __half2float(y[s3 * D + lane]);
        acc += (v0 + v1) + (v2 + v3);
    }
    for (; e < end; ++e) acc += __half2float(y[csr_src[e] * D + lane]);

    float dn = dinv[node];
    int idx = node * D + lane;
    if (FINAL == 0) {
        y_out[idx] = __float2half(dn * dn * acc);
    } else {
        float x3 = dn * acc;
        float xs = rsq[node] * (__half2float(y1[idx]) + __half2float(y2[idx]));
        out[idx] = 0.25f * (emb[idx] + xs + x3);
    }
}

extern "C" void kernel_launch(void* const* d_in, const int* in_sizes, int n_in,
                              void* d_out, int out_size, void* d_ws, size_t ws_size,
                              hipStream_t stream) {
    const int*   ei  = (const int*)d_in[0];     // (2, E) int32, row-major
    const float* emb = (const float*)d_in[1];   // (N, D) fp32
    const int* src = ei;
    const int* dst = ei + N_EDGES;
    float* out = (float*)d_out;

    // workspace layout
    int* bhist      = (int*)d_ws;                          // NBUCK
    int* bucketoff  = bhist + NBUCK;                       // NBUCK+1
    int* bnext      = bucketoff + (NBUCK + 1);             // NBUCK
    int* rowptr     = bnext + NBUCK;                       // N+1
    unsigned int*   tmp     = (unsigned int*)(rowptr + N_NODES + 1);   // E (4B)
    unsigned short* csr_src = (unsigned short*)(tmp + N_EDGES);        // E (2B)
    float* dinv = (float*)(csr_src + N_EDGES);             // N
    float* rsq  = dinv + N_NODES;                          // N
    __half* y0  = (__half*)(rsq + N_NODES);                // N*D
    __half* y1  = y0 + (size_t)N_NODES * D;                // N*D
    __half* y2  = y1 + (size_t)N_NODES * D;                // N*D

    zero_bhist<<<1, 256, 0, stream>>>(bhist);
    bucket_hist<<<512, 256, 0, stream>>>(dst, bhist);
    bucket_scan<<<1, 256, 0, stream>>>(bhist, bucketoff, bnext, rowptr);
    pass_a<<<PA_BLOCKS, 256, 0, stream>>>(src, dst, bnext, tmp);
    pass_b<<<NBUCK, 256, 0, stream>>>(tmp, bucketoff, rowptr, dinv, rsq, csr_src);
    scale_kernel<<<((N_NODES * D / 4) + 255) / 256, 256, 0, stream>>>(
        emb, dinv, y0, N_NODES * D / 4);

    const int pull_blocks = (N_NODES + 3) / 4;
    // y1 = A_s y0
    pull_kernel<0><<<pull_blocks, 256, 0, stream>>>(rowptr, csr_src, dinv, y0, y1,
                                                    nullptr, nullptr, nullptr, nullptr, nullptr);
    // y2 = A_s y1
    pull_kernel<0><<<pull_blocks, 256, 0, stream>>>(rowptr, csr_src, dinv, y1, y2,
                                                    nullptr, nullptr, nullptr, nullptr, nullptr);
    // out = 0.25*(emb + rsq*(y1+y2) + dinv*sum(y2))
    pull_kernel<1><<<pull_blocks, 256, 0, stream>>>(rowptr, csr_src, dinv, y2, nullptr,
                                                    rsq, y1, y2, emb, out);
}

// Round 7
// 141.037 us; speedup vs baseline: 4.1783x; 1.1517x over previous
//
#include <hip/hip_runtime.h>
#include <hip/hip_fp16.h>

#define N_NODES 50000
#define N_EDGES 800000
#define D 64
#define NBUCK 196                 // ceil(N_NODES / 256)
#define BUCK_SHIFT 8
#define PA_CHUNK 2048
#define PA_BLOCKS ((N_EDGES + PA_CHUNK - 1) / PA_CHUNK)   // 391
#define PB_CAP 8192               // Poisson(4082) never reaches this; fallback kept anyway

// ---- tiny init -------------------------------------------------------------
__global__ void zero_bhist(int* __restrict__ bhist) {
    int t = threadIdx.x;
    if (t < NBUCK) bhist[t] = 0;
}

// ---- coarse 196-bucket histogram of dst (LDS-privatized) -------------------
__global__ __launch_bounds__(256) void bucket_hist(const int* __restrict__ dst,
                                                   int* __restrict__ bhist) {
    __shared__ int h[NBUCK];
    for (int i = threadIdx.x; i < NBUCK; i += 256) h[i] = 0;
    __syncthreads();
    int stride = gridDim.x * 256;
    for (int e = blockIdx.x * 256 + threadIdx.x; e < N_EDGES; e += stride)
        atomicAdd(&h[dst[e] >> BUCK_SHIFT], 1);
    __syncthreads();
    for (int i = threadIdx.x; i < NBUCK; i += 256)
        if (h[i]) atomicAdd(&bhist[i], h[i]);
}

// ---- 1-block scan of 196 bucket counts -> bucketoff / bnext ---------------
__global__ __launch_bounds__(256) void bucket_scan(const int* __restrict__ bhist,
                                                   int* __restrict__ bucketoff,
                                                   int* __restrict__ bnext,
                                                   int* __restrict__ rowptr) {
    __shared__ int lds[256];
    int t = threadIdx.x;
    int v = (t < NBUCK) ? bhist[t] : 0;
    lds[t] = v;
    __syncthreads();
    for (int off = 1; off < 256; off <<= 1) {
        int u = (t >= off) ? lds[t - off] : 0;
        __syncthreads();
        lds[t] += u;
        __syncthreads();
    }
    if (t < NBUCK) { bucketoff[t] = lds[t] - v; bnext[t] = lds[t] - v; }
    if (t == 0)    { bucketoff[NBUCK] = N_EDGES; rowptr[N_NODES] = N_EDGES; }
}

// ---- pass A: bin edges by dst>>8 into tmp regions (block-privatized) -------
__global__ __launch_bounds__(256) void pass_a(const int* __restrict__ src,
                                              const int* __restrict__ dst,
                                              int* __restrict__ bnext,
                                              unsigned int* __restrict__ tmp) {
    __shared__ int cnt[NBUCK], loc[NBUCK], cur[NBUCK], gbase[NBUCK];
    __shared__ int s[256];
    __shared__ unsigned int stage[PA_CHUNK];
    __shared__ unsigned char sb[PA_CHUNK];
    int t = threadIdx.x;
    int base = blockIdx.x * PA_CHUNK;
    int len = N_EDGES - base; if (len > PA_CHUNK) len = PA_CHUNK;

    for (int i = t; i < NBUCK; i += 256) cnt[i] = 0;
    __syncthreads();
    for (int j = t; j < len; j += 256)
        atomicAdd(&cnt[dst[base + j] >> BUCK_SHIFT], 1);
    __syncthreads();
    int v = (t < NBUCK) ? cnt[t] : 0;
    s[t] = v;
    __syncthreads();
    for (int off = 1; off < 256; off <<= 1) {
        int u = (t >= off) ? s[t - off] : 0;
        __syncthreads();
        s[t] += u;
        __syncthreads();
    }
    if (t < NBUCK) {
        loc[t] = s[t] - v;
        cur[t] = s[t] - v;
        gbase[t] = v ? atomicAdd(&bnext[t], v) : 0;
    }
    __syncthreads();
    for (int j = t; j < len; j += 256) {
        int d = dst[base + j], s0 = src[base + j];
        int b = d >> BUCK_SHIFT;
        int r = atomicAdd(&cur[b], 1);
        stage[r] = ((unsigned)d << 16) | (unsigned)s0;
        sb[r] = (unsigned char)b;
    }
    __syncthreads();
    for (int j = t; j < len; j += 256) {
        int b = sb[j];
        tmp[gbase[b] + (j - loc[b])] = stage[j];
    }
}

// ---- pass B: per-bucket in-LDS counting sort -> csr_src, rowptr, dinv, rsq -
__global__ __launch_bounds__(256) void pass_b(const unsigned int* __restrict__ tmp,
                                              const int* __restrict__ bucketoff,
                                              int* __restrict__ rowptr,
                                              float* __restrict__ dinv,
                                              float* __restrict__ rsq,
                                              unsigned short* __restrict__ csr_src) {
    __shared__ int hist[256], ptr[256], cur[256];
    __shared__ unsigned int in[PB_CAP];
    __shared__ unsigned short outs[PB_CAP];
    int b = blockIdx.x, t = threadIdx.x;
    int base = bucketoff[b], end = bucketoff[b + 1];
    int k = end - base;
    int node0 = b << BUCK_SHIFT;
    int nloc = N_NODES - node0; if (nloc > 256) nloc = 256;

    hist[t] = 0;
    __syncthreads();
    bool fits = (k <= PB_CAP);
    for (int j = t; j < k; j += 256) {
        unsigned int w = tmp[base + j];
        if (fits) in[j] = w;
        atomicAdd(&hist[(w >> 16) & 255], 1);
    }
    __syncthreads();
    int v = hist[t];
    ptr[t] = v;
    __syncthreads();
    for (int off = 1; off < 256; off <<= 1) {
        int u = (t >= off) ? ptr[t - off] : 0;
        __syncthreads();
        ptr[t] += u;
        __syncthreads();
    }
    int excl = ptr[t] - v;
    cur[t] = excl;
    if (t < nloc) {
        rowptr[node0 + t] = base + excl;
        dinv[node0 + t] = v > 0 ? rsqrtf((float)v) : 0.0f;
        rsq[node0 + t]  = sqrtf((float)v);
    }
    __syncthreads();
    if (fits) {
        for (int j = t; j < k; j += 256) {
            unsigned int w = in[j];
            int r = atomicAdd(&cur[(w >> 16) & 255], 1);
            outs[r] = (unsigned short)(w & 0xFFFF);
        }
        __syncthreads();
        for (int j = t; j < k; j += 256) csr_src[base + j] = outs[j];
    } else {
        for (int j = t; j < k; j += 256) {
            unsigned int w = tmp[base + j];
            int r = atomicAdd(&cur[(w >> 16) & 255], 1);
            csr_src[base + r] = (unsigned short)(w & 0xFFFF);
        }
    }
}

// ---- y0 = dinv[node] * emb (fp16) ------------------------------------------
__global__ void scale_kernel(const float* __restrict__ emb, const float* __restrict__ dinv,
                             __half* __restrict__ y, int total4) {
    int i = blockIdx.x * blockDim.x + threadIdx.x;
    if (i < total4) {
        float4 v = ((const float4*)emb)[i];
        float s = dinv[(i * 4) / D];
        ((__half2*)y)[2 * i]     = __floats2half2_rn(v.x * s, v.y * s);
        ((__half2*)y)[2 * i + 1] = __floats2half2_rn(v.z * s, v.w * s);
    }
}

// ---- pull (one wave per dst node, lane = dim) ------------------------------
// Indices are loaded 64-at-a-time in one coalesced wave load, then extracted
// with readlane (SALU) so the inner loop issues only the row gathers.
// FINAL=0: y_out = dinv^2 * acc       (produces y_{k+1})
// FINAL=1: x3 = dinv*acc; out = 0.25*(emb + rsq*(y1+y2) + x3)
template <int FINAL>
__global__ __launch_bounds__(256) void pull_kernel(
        const int* __restrict__ rowptr, const unsigned short* __restrict__ csr_src,
        const float* __restrict__ dinv, const __half* __restrict__ y,
        __half* __restrict__ y_out,
        const float* __restrict__ rsq, const __half* __restrict__ y1,
        const __half* __restrict__ y2, const float* __restrict__ emb,
        float* __restrict__ out) {
    int node = blockIdx.x * 4 + (threadIdx.x >> 6);
    int lane = threadIdx.x & 63;
    if (node >= N_NODES) return;
    int beg = rowptr[node];
    int end = rowptr[node + 1];
    float acc = 0.0f;
    for (int e0 = beg; e0 < end; e0 += 64) {
        int kk = end - e0; if (kk > 64) kk = 64;
        // one coalesced 128B load fetches up to 64 edge indices for this wave
        int idxv = (e0 + lane < end) ? (int)csr_src[e0 + lane] : 0;
        int i = 0;
        for (; i + 3 < kk; i += 4) {
            int s0 = __builtin_amdgcn_readlane(idxv, i);
            int s1 = __builtin_amdgcn_readlane(idxv, i + 1);
            int s2 = __builtin_amdgcn_readlane(idxv, i + 2);
            int s3 = __builtin_amdgcn_readlane(idxv, i + 3);
            float v0 = __half2float(y[s0 * D + lane]);
            float v1 = __half2float(y[s1 * D + lane]);
            float v2 = __half2float(y[s2 * D + lane]);
            float v3 = __half2float(y[s3 * D + lane]);
            acc += (v0 + v1) + (v2 + v3);
        }
        for (; i < kk; ++i) {
            int s0 = __builtin_amdgcn_readlane(idxv, i);
            acc += __half2float(y[s0 * D + lane]);
        }
    }

    float dn = dinv[node];
    int idx = node * D + lane;
    if (FINAL == 0) {
        y_out[idx] = __float2half(dn * dn * acc);
    } else {
        float x3 = dn * acc;
        float xs = rsq[node] * (__half2float(y1[idx]) + __half2float(y2[idx]));
        out[idx] = 0.25f * (emb[idx] + xs + x3);
    }
}

extern "C" void kernel_launch(void* const* d_in, const int* in_sizes, int n_in,
                              void* d_out, int out_size, void* d_ws, size_t ws_size,
                              hipStream_t stream) {
    const int*   ei  = (const int*)d_in[0];     // (2, E) int32, row-major
    const float* emb = (const float*)d_in[1];   // (N, D) fp32
    const int* src = ei;
    const int* dst = ei + N_EDGES;
    float* out = (float*)d_out;

    // workspace layout
    int* bhist      = (int*)d_ws;                          // NBUCK
    int* bucketoff  = bhist + NBUCK;                       // NBUCK+1
    int* bnext      = bucketoff + (NBUCK + 1);             // NBUCK
    int* rowptr     = bnext + NBUCK;                       // N+1
    unsigned int*   tmp     = (unsigned int*)(rowptr + N_NODES + 1);   // E (4B)
    unsigned short* csr_src = (unsigned short*)(tmp + N_EDGES);        // E (2B)
    float* dinv = (float*)(csr_src + N_EDGES);             // N
    float* rsq  = dinv + N_NODES;                          // N
    __half* y0  = (__half*)(rsq + N_NODES);                // N*D
    __half* y1  = y0 + (size_t)N_NODES * D;                // N*D
    __half* y2  = y1 + (size_t)N_NODES * D;                // N*D

    zero_bhist<<<1, 256, 0, stream>>>(bhist);
    bucket_hist<<<512, 256, 0, stream>>>(dst, bhist);
    bucket_scan<<<1, 256, 0, stream>>>(bhist, bucketoff, bnext, rowptr);
    pass_a<<<PA_BLOCKS, 256, 0, stream>>>(src, dst, bnext, tmp);
    pass_b<<<NBUCK, 256, 0, stream>>>(tmp, bucketoff, rowptr, dinv, rsq, csr_src);
    scale_kernel<<<((N_NODES * D / 4) + 255) / 256, 256, 0, stream>>>(
        emb, dinv, y0, N_NODES * D / 4);

    const int pull_blocks = (N_NODES + 3) / 4;
    // y1 = A_s y0
    pull_kernel<0><<<pull_blocks, 256, 0, stream>>>(rowptr, csr_src, dinv, y0, y1,
                                                    nullptr, nullptr, nullptr, nullptr, nullptr);
    // y2 = A_s y1
    pull_kernel<0><<<pull_blocks, 256, 0, stream>>>(rowptr, csr_src, dinv, y1, y2,
                                                    nullptr, nullptr, nullptr, nullptr, nullptr);
    // out = 0.25*(emb + rsq*(y1+y2) + dinv*sum(y2))
    pull_kernel<1><<<pull_blocks, 256, 0, stream>>>(rowptr, csr_src, dinv, y2, nullptr,
                                                    rsq, y1, y2, emb, out);
}

// Round 8
// 133.248 us; speedup vs baseline: 4.4225x; 1.0585x over previous
//
#include <hip/hip_runtime.h>
#include <hip/hip_fp16.h>

#define N_NODES 50000
#define N_EDGES 800000
#define D 64
#define NBUCK 196                 // ceil(N_NODES / 256)
#define BUCK_SHIFT 8
#define PA_CHUNK 2048
#define PA_BLOCKS ((N_EDGES + PA_CHUNK - 1) / PA_CHUNK)   // 391
#define PB_CAP 8192               // Poisson(4082) never reaches this; fallback kept anyway

// ---- tiny init -------------------------------------------------------------
__global__ void zero_bhist(int* __restrict__ bhist) {
    int t = threadIdx.x;
    if (t < NBUCK) bhist[t] = 0;
}

// ---- coarse 196-bucket histogram of dst (LDS-privatized) -------------------
__global__ __launch_bounds__(256) void bucket_hist(const int* __restrict__ dst,
                                                   int* __restrict__ bhist) {
    __shared__ int h[NBUCK];
    for (int i = threadIdx.x; i < NBUCK; i += 256) h[i] = 0;
    __syncthreads();
    int stride = gridDim.x * 256;
    for (int e = blockIdx.x * 256 + threadIdx.x; e < N_EDGES; e += stride)
        atomicAdd(&h[dst[e] >> BUCK_SHIFT], 1);
    __syncthreads();
    for (int i = threadIdx.x; i < NBUCK; i += 256)
        if (h[i]) atomicAdd(&bhist[i], h[i]);
}

// ---- 1-block scan of 196 bucket counts -> bucketoff / bnext ---------------
__global__ __launch_bounds__(256) void bucket_scan(const int* __restrict__ bhist,
                                                   int* __restrict__ bucketoff,
                                                   int* __restrict__ bnext,
                                                   int* __restrict__ rowptr) {
    __shared__ int lds[256];
    int t = threadIdx.x;
    int v = (t < NBUCK) ? bhist[t] : 0;
    lds[t] = v;
    __syncthreads();
    for (int off = 1; off < 256; off <<= 1) {
        int u = (t >= off) ? lds[t - off] : 0;
        __syncthreads();
        lds[t] += u;
        __syncthreads();
    }
    if (t < NBUCK) { bucketoff[t] = lds[t] - v; bnext[t] = lds[t] - v; }
    if (t == 0)    { bucketoff[NBUCK] = N_EDGES; rowptr[N_NODES] = N_EDGES; }
}

// ---- pass A: bin edges by dst>>8 into tmp regions (block-privatized) -------
__global__ __launch_bounds__(256) void pass_a(const int* __restrict__ src,
                                              const int* __restrict__ dst,
                                              int* __restrict__ bnext,
                                              unsigned int* __restrict__ tmp) {
    __shared__ int cnt[NBUCK], loc[NBUCK], cur[NBUCK], gbase[NBUCK];
    __shared__ int s[256];
    __shared__ unsigned int stage[PA_CHUNK];
    __shared__ unsigned char sb[PA_CHUNK];
    int t = threadIdx.x;
    int base = blockIdx.x * PA_CHUNK;
    int len = N_EDGES - base; if (len > PA_CHUNK) len = PA_CHUNK;

    for (int i = t; i < NBUCK; i += 256) cnt[i] = 0;
    __syncthreads();
    for (int j = t; j < len; j += 256)
        atomicAdd(&cnt[dst[base + j] >> BUCK_SHIFT], 1);
    __syncthreads();
    int v = (t < NBUCK) ? cnt[t] : 0;
    s[t] = v;
    __syncthreads();
    for (int off = 1; off < 256; off <<= 1) {
        int u = (t >= off) ? s[t - off] : 0;
        __syncthreads();
        s[t] += u;
        __syncthreads();
    }
    if (t < NBUCK) {
        loc[t] = s[t] - v;
        cur[t] = s[t] - v;
        gbase[t] = v ? atomicAdd(&bnext[t], v) : 0;
    }
    __syncthreads();
    for (int j = t; j < len; j += 256) {
        int d = dst[base + j], s0 = src[base + j];
        int b = d >> BUCK_SHIFT;
        int r = atomicAdd(&cur[b], 1);
        stage[r] = ((unsigned)d << 16) | (unsigned)s0;
        sb[r] = (unsigned char)b;
    }
    __syncthreads();
    for (int j = t; j < len; j += 256) {
        int b = sb[j];
        tmp[gbase[b] + (j - loc[b])] = stage[j];
    }
}

// ---- pass B: per-bucket in-LDS counting sort -> csr_src, rowptr, dinv, rsq -
__global__ __launch_bounds__(256) void pass_b(const unsigned int* __restrict__ tmp,
                                              const int* __restrict__ bucketoff,
                                              int* __restrict__ rowptr,
                                              float* __restrict__ dinv,
                                              float* __restrict__ rsq,
                                              unsigned short* __restrict__ csr_src) {
    __shared__ int hist[256], ptr[256], cur[256];
    __shared__ unsigned int in[PB_CAP];
    __shared__ unsigned short outs[PB_CAP];
    int b = blockIdx.x, t = threadIdx.x;
    int base = bucketoff[b], end = bucketoff[b + 1];
    int k = end - base;
    int node0 = b << BUCK_SHIFT;
    int nloc = N_NODES - node0; if (nloc > 256) nloc = 256;

    hist[t] = 0;
    __syncthreads();
    bool fits = (k <= PB_CAP);
    for (int j = t; j < k; j += 256) {
        unsigned int w = tmp[base + j];
        if (fits) in[j] = w;
        atomicAdd(&hist[(w >> 16) & 255], 1);
    }
    __syncthreads();
    int v = hist[t];
    ptr[t] = v;
    __syncthreads();
    for (int off = 1; off < 256; off <<= 1) {
        int u = (t >= off) ? ptr[t - off] : 0;
        __syncthreads();
        ptr[t] += u;
        __syncthreads();
    }
    int excl = ptr[t] - v;
    cur[t] = excl;
    if (t < nloc) {
        rowptr[node0 + t] = base + excl;
        dinv[node0 + t] = v > 0 ? rsqrtf((float)v) : 0.0f;
        rsq[node0 + t]  = sqrtf((float)v);
    }
    __syncthreads();
    if (fits) {
        for (int j = t; j < k; j += 256) {
            unsigned int w = in[j];
            int r = atomicAdd(&cur[(w >> 16) & 255], 1);
            outs[r] = (unsigned short)(w & 0xFFFF);
        }
        __syncthreads();
        for (int j = t; j < k; j += 256) csr_src[base + j] = outs[j];
    } else {
        for (int j = t; j < k; j += 256) {
            unsigned int w = tmp[base + j];
            int r = atomicAdd(&cur[(w >> 16) & 255], 1);
            csr_src[base + r] = (unsigned short)(w & 0xFFFF);
        }
    }
}

// ---- y0 = dinv[node] * emb (fp16) ------------------------------------------
__global__ void scale_kernel(const float* __restrict__ emb, const float* __restrict__ dinv,
                             __half* __restrict__ y, int total4) {
    int i = blockIdx.x * blockDim.x + threadIdx.x;
    if (i < total4) {
        float4 v = ((const float4*)emb)[i];
        float s = dinv[(i * 4) / D];
        ((__half2*)y)[2 * i]     = __floats2half2_rn(v.x * s, v.y * s);
        ((__half2*)y)[2 * i + 1] = __floats2half2_rn(v.z * s, v.w * s);
    }
}

// ---- pull: one wave per dst node; 8 lane-groups x 8 dims; 8 edges/gather ---
// Each 8-lane group g handles edges 8i+g of the node; lane gl holds dims
// gl*8..gl*8+7 as dwordx4 (8 fp16). One VMEM instr fetches 8 full rows.
// FINAL=0: y_out = dinv^2 * acc
// FINAL=1: x3 = dinv*acc; out = 0.25*(emb + rsq*(y1+y2) + x3)
template <int FINAL>
__global__ __launch_bounds__(256) void pull_kernel(
        const int* __restrict__ rowptr, const unsigned short* __restrict__ csr_src,
        const float* __restrict__ dinv, const __half* __restrict__ y,
        __half* __restrict__ y_out,
        const float* __restrict__ rsq, const __half* __restrict__ y1,
        const __half* __restrict__ y2, const float* __restrict__ emb,
        float* __restrict__ out) {
    int node = blockIdx.x * 4 + (threadIdx.x >> 6);
    int lane = threadIdx.x & 63;
    if (node >= N_NODES) return;
    int beg = rowptr[node];
    int end = rowptr[node + 1];
    int g  = lane >> 3;     // group 0..7 (edge slot within chunk)
    int gl = lane & 7;      // lane in group (dim block)

    float acc0 = 0.f, acc1 = 0.f, acc2 = 0.f, acc3 = 0.f;
    float acc4 = 0.f, acc5 = 0.f, acc6 = 0.f, acc7 = 0.f;

    for (int e0 = beg; e0 < end; e0 += 64) {
        int kk = end - e0; if (kk > 64) kk = 64;
        // one coalesced 128B load fetches up to 64 edge indices for this wave
        int idxv = (e0 + lane < end) ? (int)csr_src[e0 + lane] : 0;
        int nch = (kk + 7) >> 3;
        for (int i = 0; i < nch; ++i) {
            int pos = 8 * i + g;
            int s = __shfl(idxv, pos, 64);   // group's src node for this chunk
            if (pos < kk) {
                const uint4* p = (const uint4*)(y + (size_t)s * D + gl * 8);
                uint4 v = *p;                 // 8 fp16 dims
                const __half2* h = (const __half2*)&v;
                float2 f0 = __half22float2(h[0]);
                float2 f1 = __half22float2(h[1]);
                float2 f2 = __half22float2(h[2]);
                float2 f3 = __half22float2(h[3]);
                acc0 += f0.x; acc1 += f0.y; acc2 += f1.x; acc3 += f1.y;
                acc4 += f2.x; acc5 += f2.y; acc6 += f3.x; acc7 += f3.y;
            }
        }
    }

    // cross-group reduce: groups hold partial sums of the same 8 dims
    #pragma unroll
    for (int off = 8; off < 64; off <<= 1) {
        acc0 += __shfl_xor(acc0, off, 64);
        acc1 += __shfl_xor(acc1, off, 64);
        acc2 += __shfl_xor(acc2, off, 64);
        acc3 += __shfl_xor(acc3, off, 64);
        acc4 += __shfl_xor(acc4, off, 64);
        acc5 += __shfl_xor(acc5, off, 64);
        acc6 += __shfl_xor(acc6, off, 64);
        acc7 += __shfl_xor(acc7, off, 64);
    }

    if (g == 0) {   // lanes 0..7 own dims gl*8..gl*8+7
        float dn = dinv[node];
        int base = node * D + gl * 8;
        if (FINAL == 0) {
            float s2 = dn * dn;
            __half2 h[4];
            h[0] = __floats2half2_rn(acc0 * s2, acc1 * s2);
            h[1] = __floats2half2_rn(acc2 * s2, acc3 * s2);
            h[2] = __floats2half2_rn(acc4 * s2, acc5 * s2);
            h[3] = __floats2half2_rn(acc6 * s2, acc7 * s2);
            *(uint4*)(y_out + base) = *(const uint4*)h;
        } else {
            float rs = rsq[node];
            uint4 v1 = *(const uint4*)(y1 + base);
            uint4 v2 = *(const uint4*)(y2 + base);
            const __half2* h1 = (const __half2*)&v1;
            const __half2* h2 = (const __half2*)&v2;
            float4 ea = *(const float4*)(emb + base);
            float4 eb = *(const float4*)(emb + base + 4);
            float2 a0 = __half22float2(h1[0]), b0 = __half22float2(h2[0]);
            float2 a1 = __half22float2(h1[1]), b1 = __half22float2(h2[1]);
            float2 a2 = __half22float2(h1[2]), b2 = __half22float2(h2[2]);
            float2 a3 = __half22float2(h1[3]), b3 = __half22float2(h2[3]);
            float4 o0, o1;
            o0.x = 0.25f * (ea.x + rs * (a0.x + b0.x) + dn * acc0);
            o0.y = 0.25f * (ea.y + rs * (a0.y + b0.y) + dn * acc1);
            o0.z = 0.25f * (ea.z + rs * (a1.x + b1.x) + dn * acc2);
            o0.w = 0.25f * (ea.w + rs * (a1.y + b1.y) + dn * acc3);
            o1.x = 0.25f * (eb.x + rs * (a2.x + b2.x) + dn * acc4);
            o1.y = 0.25f * (eb.y + rs * (a2.y + b2.y) + dn * acc5);
            o1.z = 0.25f * (eb.z + rs * (a3.x + b3.x) + dn * acc6);
            o1.w = 0.25f * (eb.w + rs * (a3.y + b3.y) + dn * acc7);
            *(float4*)(out + base)     = o0;
            *(float4*)(out + base + 4) = o1;
        }
    }
}

extern "C" void kernel_launch(void* const* d_in, const int* in_sizes, int n_in,
                              void* d_out, int out_size, void* d_ws, size_t ws_size,
                              hipStream_t stream) {
    const int*   ei  = (const int*)d_in[0];     // (2, E) int32, row-major
    const float* emb = (const float*)d_in[1];   // (N, D) fp32
    const int* src = ei;
    const int* dst = ei + N_EDGES;
    float* out = (float*)d_out;

    // workspace layout
    int* bhist      = (int*)d_ws;                          // NBUCK
    int* bucketoff  = bhist + NBUCK;                       // NBUCK+1
    int* bnext      = bucketoff + (NBUCK + 1);             // NBUCK
    int* rowptr     = bnext + NBUCK;                       // N+1
    unsigned int*   tmp     = (unsigned int*)(rowptr + N_NODES + 1);   // E (4B)
    unsigned short* csr_src = (unsigned short*)(tmp + N_EDGES);        // E (2B)
    float* dinv = (float*)(csr_src + N_EDGES);             // N
    float* rsq  = dinv + N_NODES;                          // N
    __half* y0  = (__half*)(rsq + N_NODES);                // N*D
    __half* y1  = y0 + (size_t)N_NODES * D;                // N*D
    __half* y2  = y1 + (size_t)N_NODES * D;                // N*D

    zero_bhist<<<1, 256, 0, stream>>>(bhist);
    bucket_hist<<<512, 256, 0, stream>>>(dst, bhist);
    bucket_scan<<<1, 256, 0, stream>>>(bhist, bucketoff, bnext, rowptr);
    pass_a<<<PA_BLOCKS, 256, 0, stream>>>(src, dst, bnext, tmp);
    pass_b<<<NBUCK, 256, 0, stream>>>(tmp, bucketoff, rowptr, dinv, rsq, csr_src);
    scale_kernel<<<((N_NODES * D / 4) + 255) / 256, 256, 0, stream>>>(
        emb, dinv, y0, N_NODES * D / 4);

    const int pull_blocks = (N_NODES + 3) / 4;
    // y1 = A_s y0
    pull_kernel<0><<<pull_blocks, 256, 0, stream>>>(rowptr, csr_src, dinv, y0, y1,
                                                    nullptr, nullptr, nullptr, nullptr, nullptr);
    // y2 = A_s y1
    pull_kernel<0><<<pull_blocks, 256, 0, stream>>>(rowptr, csr_src, dinv, y1, y2,
                                                    nullptr, nullptr, nullptr, nullptr, nullptr);
    // out = 0.25*(emb + rsq*(y1+y2) + dinv*sum(y2))
    pull_kernel<1><<<pull_blocks, 256, 0, stream>>>(rowptr, csr_src, dinv, y2, nullptr,
                                                    rsq, y1, y2, emb, out);
}